// Round 1
// baseline (415.334 us; speedup 1.0000x reference)
//
#include <hip/hip_runtime.h>

// out = exp(Q K^T) V, unnormalized. B=4, S=4096, D=64, fp32.
// Vector-ALU baseline: no fp32 MFMA on CDNA4, so this rooflines at
// 17.2 GFLOP / 157.3 TF ~= 110us. One block per (batch, 64-row Q tile),
// 64-wide K/V tiles staged in LDS, 4x4 register micro-tile per thread.

constexpr int S  = 4096;
constexpr int D  = 64;
constexpr int BQ = 64;   // Q rows per block
constexpr int BK = 64;   // K/V rows per tile

__global__ __launch_bounds__(256, 1) void attn_exp_kernel(
    const float* __restrict__ q, const float* __restrict__ k,
    const float* __restrict__ v, float* __restrict__ out)
{
    // 4 x 16 KiB = 64 KiB LDS exactly. All GEMM reads use a wave-uniform
    // k-index, so row stride 64 (no pad) is conflict-free on reads and
    // keeps float4 (16B) alignment everywhere.
    __shared__ float Qt[D][BQ];    // Qt[d][m]   (Q transposed)
    __shared__ float Kt[D][BK];    // Kt[d][n]   (K transposed)
    __shared__ float Vs[BK][D];    // Vs[kk][c]  (V natural)
    __shared__ float Pt[BK][BQ];   // Pt[kk][m]  (exp(S) transposed)

    const int tid = threadIdx.x;
    const int tx  = tid & 15;      // column group 0..15
    const int ty  = tid >> 4;      // row group 0..15
    const int b   = blockIdx.y;
    const int q0  = blockIdx.x * BQ;

    const float* qb = q + ((size_t)b * S + q0) * D;
    const float* kb = k + (size_t)b * S * D;
    const float* vb = v + (size_t)b * S * D;
    float*       ob = out + ((size_t)b * S + q0) * D;

    // ---- stage Q tile, transposed: 64x64 floats, 4 float4 loads/thread ----
    #pragma unroll
    for (int i = 0; i < 4; ++i) {
        int idx = i * 256 + tid;
        int m   = idx >> 4;          // 0..63
        int d4  = (idx & 15) << 2;   // 0,4,..,60
        float4 val = *(const float4*)(qb + m * D + d4);
        Qt[d4 + 0][m] = val.x;
        Qt[d4 + 1][m] = val.y;
        Qt[d4 + 2][m] = val.z;
        Qt[d4 + 3][m] = val.w;
    }

    float o[4][4];
    #pragma unroll
    for (int i = 0; i < 4; ++i)
        #pragma unroll
        for (int j = 0; j < 4; ++j) o[i][j] = 0.0f;

    for (int t = 0; t < S / BK; ++t) {
        // barrier: previous iteration's PV GEMM done before Kt/Vs overwrite
        // (also covers the initial Qt staging on t==0)
        __syncthreads();

        const float* kt = kb + (size_t)t * BK * D;
        const float* vt = vb + (size_t)t * BK * D;
        #pragma unroll
        for (int i = 0; i < 4; ++i) {
            int idx = i * 256 + tid;
            int n   = idx >> 4;
            int d4  = (idx & 15) << 2;
            float4 kv = *(const float4*)(kt + n * D + d4);
            Kt[d4 + 0][n] = kv.x;
            Kt[d4 + 1][n] = kv.y;
            Kt[d4 + 2][n] = kv.z;
            Kt[d4 + 3][n] = kv.w;
            float4 vv = *(const float4*)(vt + n * D + d4);
            *(float4*)&Vs[n][d4] = vv;
        }
        __syncthreads();

        // ---- GEMM1: s[r][c] = sum_d Q[r][d] * K[c][d] ----
        float s[4][4];
        #pragma unroll
        for (int i = 0; i < 4; ++i)
            #pragma unroll
            for (int j = 0; j < 4; ++j) s[i][j] = 0.0f;

        #pragma unroll 8
        for (int d = 0; d < D; ++d) {
            float4 a  = *(const float4*)&Qt[d][ty << 2];
            float4 bb = *(const float4*)&Kt[d][tx << 2];
            s[0][0] += a.x * bb.x; s[0][1] += a.x * bb.y; s[0][2] += a.x * bb.z; s[0][3] += a.x * bb.w;
            s[1][0] += a.y * bb.x; s[1][1] += a.y * bb.y; s[1][2] += a.y * bb.z; s[1][3] += a.y * bb.w;
            s[2][0] += a.z * bb.x; s[2][1] += a.z * bb.y; s[2][2] += a.z * bb.z; s[2][3] += a.z * bb.w;
            s[3][0] += a.w * bb.x; s[3][1] += a.w * bb.y; s[3][2] += a.w * bb.z; s[3][3] += a.w * bb.w;
        }

        // ---- P = exp(S), written transposed for the PV GEMM ----
        #pragma unroll
        for (int j = 0; j < 4; ++j) {
            float4 pj;
            pj.x = __expf(s[0][j]);
            pj.y = __expf(s[1][j]);
            pj.z = __expf(s[2][j]);
            pj.w = __expf(s[3][j]);
            *(float4*)&Pt[(tx << 2) + j][ty << 2] = pj;
        }
        __syncthreads();

        // ---- GEMM2: o[r][c] += sum_kk P[r][kk] * V[kk][c] ----
        #pragma unroll 8
        for (int kk = 0; kk < BK; ++kk) {
            float4 a  = *(const float4*)&Pt[kk][ty << 2];
            float4 bb = *(const float4*)&Vs[kk][tx << 2];
            o[0][0] += a.x * bb.x; o[0][1] += a.x * bb.y; o[0][2] += a.x * bb.z; o[0][3] += a.x * bb.w;
            o[1][0] += a.y * bb.x; o[1][1] += a.y * bb.y; o[1][2] += a.y * bb.z; o[1][3] += a.y * bb.w;
            o[2][0] += a.z * bb.x; o[2][1] += a.z * bb.y; o[2][2] += a.z * bb.z; o[2][3] += a.z * bb.w;
            o[3][0] += a.w * bb.x; o[3][1] += a.w * bb.y; o[3][2] += a.w * bb.z; o[3][3] += a.w * bb.w;
        }
    }

    #pragma unroll
    for (int i = 0; i < 4; ++i) {
        float4 r = make_float4(o[i][0], o[i][1], o[i][2], o[i][3]);
        *(float4*)(ob + ((ty << 2) + i) * D + (tx << 2)) = r;
    }
}

extern "C" void kernel_launch(void* const* d_in, const int* in_sizes, int n_in,
                              void* d_out, int out_size, void* d_ws, size_t ws_size,
                              hipStream_t stream) {
    const float* q = (const float*)d_in[0];
    const float* k = (const float*)d_in[1];
    const float* v = (const float*)d_in[2];
    float* out = (float*)d_out;

    const int nbatch = in_sizes[0] / (S * D);   // 4
    dim3 grid(S / BQ, nbatch);
    dim3 block(256);
    attn_exp_kernel<<<grid, block, 0, stream>>>(q, k, v, out);
}

// Round 2
// 149.089 us; speedup vs baseline: 2.7858x; 2.7858x over previous
//
#include <hip/hip_runtime.h>

// out = exp(Q K^T) V, unnormalized. B=4, S=4096, D=64, fp32 in/out.
// MFMA path (v_mfma_f32_16x16x32_bf16):
//   GEMM1: S^T = K * Q^T with 3-term bf16 hi/lo split (score err ~1e-4,
//          exp amplifies score error so raw bf16 (delta~0.03) is too risky
//          against the 2% absmax threshold).
//   exp in fp32 (C/D layout), packed ds_write_b64 into P[m][kk] -- S^T's
//          C-layout (4 consecutive kk per lane) lands exactly in GEMM2's
//          A-frag layout. No scatter, no extra transpose.
//   GEMM2: O += P * V, P/V single bf16 (<=0.4% output err, 5x margin).
// 1024 threads = 16 waves (4/SIMD for latency hiding), 256 blocks = 1/CU.

typedef short s16x8 __attribute__((ext_vector_type(8)));
typedef short s16x4 __attribute__((ext_vector_type(4)));
typedef float fx4   __attribute__((ext_vector_type(4)));

constexpr int S  = 4096;
constexpr int D  = 64;
constexpr int BQ = 64;   // Q rows per block
constexpr int BN = 64;   // K/V rows per tile

__device__ __forceinline__ unsigned short f2bf(float x) {
    unsigned u = __float_as_uint(x);
    u = (u + 0x7FFFu + ((u >> 16) & 1u)) >> 16;   // RNE
    return (unsigned short)u;
}
__device__ __forceinline__ float bf2f(unsigned short h) {
    return __uint_as_float(((unsigned)h) << 16);
}

__global__ __launch_bounds__(1024) void attn_mfma_kernel(
    const float* __restrict__ q, const float* __restrict__ k,
    const float* __restrict__ v, float* __restrict__ out)
{
    // Strides chosen for 16B-aligned b128 reads + <=2-way bank aliasing:
    //  72 (144B = 36dw): rows rotate 4 banks -> 2-way on 16-lane reads, 16B-aligned.
    //  68 (136B = 34dw): Vt writes conflict-free; reads done as 2x b64 (8B-aligned).
    __shared__ unsigned short Kh[BN][72];
    __shared__ unsigned short Kl[BN][72];
    __shared__ unsigned short Vt[D][68];    // Vt[d][kk]
    __shared__ unsigned short Pm[BQ][72];   // P[m][kk], bf16

    const int tid  = threadIdx.x;
    const int lane = tid & 63;
    const int wave = tid >> 6;
    const int quad = lane >> 4;
    const int tq   = lane & 15;
    // GEMM1 wave tile: S^T[kkb*16.., mba*16..]; GEMM2 tile: O[mbb*16.., dbb*16..]
    const int kkb = wave & 3, mba = wave >> 2;
    const int dbb = wave & 3, mbb = wave >> 2;

    const int b  = blockIdx.y;
    const int q0 = blockIdx.x * BQ;
    const float* qb = q + (size_t)b * S * D;
    const float* kb = k + (size_t)b * S * D;
    const float* vb = v + (size_t)b * S * D;
    float*       ob = out + (size_t)b * S * D;

    // ---- Q fragments (hi/lo bf16 split), resident in registers ----
    // B-frag for GEMM1: B[k=quad*8+j][n=tq] = Q[row=mba*16+tq][d=ks*32+quad*8+j]
    s16x8 qh[2], ql[2];
    {
        const float* qrow = qb + (size_t)(q0 + mba * 16 + tq) * D;
        #pragma unroll
        for (int ks = 0; ks < 2; ++ks) {
            const float* src = qrow + ks * 32 + quad * 8;
            float4 f0 = *(const float4*)(src);
            float4 f1 = *(const float4*)(src + 4);
            float f[8] = {f0.x, f0.y, f0.z, f0.w, f1.x, f1.y, f1.z, f1.w};
            #pragma unroll
            for (int j = 0; j < 8; ++j) {
                unsigned short h = f2bf(f[j]);
                qh[ks][j] = (short)h;
                ql[ks][j] = (short)f2bf(f[j] - bf2f(h));
            }
        }
    }

    fx4 oacc = {0.f, 0.f, 0.f, 0.f};

    const int krow = tid >> 4;          // 0..63
    const int kc4  = (tid & 15) << 2;   // 0,4,..,60
    const int vd   = tid & 63;          // 0..63 (coalesced column id)
    const int vk   = (tid >> 6) << 2;   // 0,4,..,60

    for (int t = 0; t < S / BN; ++t) {
        __syncthreads();   // prev iter's GEMMs done before restaging

        // ---- stage K tile (hi/lo bf16) ----
        {
            const float* ksrc = kb + (size_t)(t * BN + krow) * D + kc4;
            float4 kv = *(const float4*)ksrc;
            unsigned short h0 = f2bf(kv.x), h1 = f2bf(kv.y),
                           h2 = f2bf(kv.z), h3 = f2bf(kv.w);
            s16x4 kh4 = {(short)h0, (short)h1, (short)h2, (short)h3};
            s16x4 kl4 = {(short)f2bf(kv.x - bf2f(h0)), (short)f2bf(kv.y - bf2f(h1)),
                         (short)f2bf(kv.z - bf2f(h2)), (short)f2bf(kv.w - bf2f(h3))};
            *(s16x4*)&Kh[krow][kc4] = kh4;
            *(s16x4*)&Kl[krow][kc4] = kl4;

            // ---- stage V transposed: Vt[d][kk] ----
            // 4 coalesced row-loads (lane = column d), packed b64 write.
            const float* vsrc = vb + (size_t)(t * BN + vk) * D + vd;
            s16x4 vv = {(short)f2bf(vsrc[0]),     (short)f2bf(vsrc[D]),
                        (short)f2bf(vsrc[2 * D]), (short)f2bf(vsrc[3 * D])};
            *(s16x4*)&Vt[vd][vk] = vv;
        }
        __syncthreads();

        // ---- GEMM1: S^T tile [16 kk x 16 m], contraction d = 64 ----
        fx4 sacc = {0.f, 0.f, 0.f, 0.f};
        #pragma unroll
        for (int ks = 0; ks < 2; ++ks) {
            s16x8 kah = *(const s16x8*)&Kh[kkb * 16 + tq][ks * 32 + quad * 8];
            s16x8 kal = *(const s16x8*)&Kl[kkb * 16 + tq][ks * 32 + quad * 8];
            sacc = __builtin_amdgcn_mfma_f32_16x16x32_bf16(kah, qh[ks], sacc, 0, 0, 0);
            sacc = __builtin_amdgcn_mfma_f32_16x16x32_bf16(kah, ql[ks], sacc, 0, 0, 0);
            sacc = __builtin_amdgcn_mfma_f32_16x16x32_bf16(kal, qh[ks], sacc, 0, 0, 0);
        }

        // ---- P = exp(S^T): lane holds S^T[kk=kkb*16+quad*4+r][m=mba*16+tq]
        // 4 consecutive kk at fixed m -> one b64 write into Pm[m][kk].
        s16x4 pp = {(short)f2bf(__expf(sacc[0])), (short)f2bf(__expf(sacc[1])),
                    (short)f2bf(__expf(sacc[2])), (short)f2bf(__expf(sacc[3]))};
        *(s16x4*)&Pm[mba * 16 + tq][kkb * 16 + (quad << 2)] = pp;
        __syncthreads();

        // ---- GEMM2: O tile [16 m x 16 d] += P * V, contraction kk = 64 ----
        #pragma unroll
        for (int ks = 0; ks < 2; ++ks) {
            s16x8 pa = *(const s16x8*)&Pm[mbb * 16 + tq][ks * 32 + quad * 8];
            const unsigned short* vr = &Vt[dbb * 16 + tq][ks * 32 + quad * 8];
            s16x4 va  = *(const s16x4*)vr;
            s16x4 vb2 = *(const s16x4*)(vr + 4);
            s16x8 vfull = __builtin_shufflevector(va, vb2, 0, 1, 2, 3, 4, 5, 6, 7);
            oacc = __builtin_amdgcn_mfma_f32_16x16x32_bf16(pa, vfull, oacc, 0, 0, 0);
        }
    }

    // ---- epilogue: C-layout store (row = quad*4+r, col = tq) ----
    #pragma unroll
    for (int r = 0; r < 4; ++r) {
        ob[(size_t)(q0 + mbb * 16 + quad * 4 + r) * D + dbb * 16 + tq] = oacc[r];
    }
}

extern "C" void kernel_launch(void* const* d_in, const int* in_sizes, int n_in,
                              void* d_out, int out_size, void* d_ws, size_t ws_size,
                              hipStream_t stream) {
    const float* q = (const float*)d_in[0];
    const float* k = (const float*)d_in[1];
    const float* v = (const float*)d_in[2];
    float* out = (float*)d_out;

    const int nbatch = in_sizes[0] / (S * D);   // 4
    dim3 grid(S / BQ, nbatch);
    dim3 block(1024);
    attn_mfma_kernel<<<grid, block, 0, stream>>>(q, k, v, out);
}

// Round 3
// 106.310 us; speedup vs baseline: 3.9068x; 1.4024x over previous
//
#include <hip/hip_runtime.h>

// out = exp(Q K^T) V, unnormalized. B=4, S=4096, D=64, fp32 in/out.
// Round 3: latency-structured rewrite.
//  - prep kernel: K -> fp16, V -> bf16, in MFMA-fragment order per 128-kk tile
//    (so staging is pure global_load_lds width-16 DMA, and all LDS fragment
//    reads are base+lane*16 -> conflict-free).
//  - main: BQ=64 Q-rows/block, BN=128 kk/tile, 512 thr (8 waves), K/V double-
//    buffered, DMA for tile t+1 issued right after loop-top barrier -> full-
//    iteration latency cover. Mid-iteration barrier is raw lgkmcnt-only so it
//    does NOT drain the in-flight DMA (vmcnt).
//  - GEMM1 in fp16 single-pass (scores err ~3e-3, exp-amplified -> ~0.6% out,
//    vs 2% threshold). GEMM2 bf16 (P up to e^41 overflows fp16; bf16 fine).

typedef short    s16x4 __attribute__((ext_vector_type(4)));
typedef short    s16x8 __attribute__((ext_vector_type(8)));
typedef _Float16 h16x8 __attribute__((ext_vector_type(8)));
typedef float    fx4   __attribute__((ext_vector_type(4)));

constexpr int S = 4096, D = 64, BQ = 64, BN = 128;
constexpr int TILES  = S / BN;   // 32
constexpr int CHUNKS = 16;       // 16 chunks x 64 lanes x 16B = 16KB per tile buf
constexpr int BATCH_HALVES = S * D;            // per-batch elements (1M)
constexpr int TILE_STRIDE  = TILES * CHUNKS * 64 * 8;  // 262144 halves per batch

__device__ __forceinline__ unsigned short f2bf(float x) {
    unsigned u = __float_as_uint(x);
    u = (u + 0x7FFFu + ((u >> 16) & 1u)) >> 16;   // RNE
    return (unsigned short)u;
}
__device__ __forceinline__ float bf2f(unsigned short h) {
    return __uint_as_float(((unsigned)h) << 16);
}
__device__ __forceinline__ unsigned short f2h(float x) {
    union { _Float16 h; unsigned short s; } u;
    u.h = (_Float16)x;
    return u.s;
}

// ---------------- prep: K -> fp16 frag-order, V -> bf16 frag-order ----------
// K chunk c = s*2+ks (s = 16-row subtile 0..7, ks = 32-d half):
//   kf[((b*32+t)*16+c)*64+l][j] = K[b][t*128 + s*16 + (l&15)][ks*32 + (l>>4)*8 + j]
// V chunk c2 = ks2*4+t4 (ks2 = 32-kk step, t4 = 16-d subtile):
//   vfr[...+l][j] = V[b][t*128 + ks2*32 + (l>>4)*8 + j][t4*16 + (l&15)]
__global__ __launch_bounds__(256) void prep_kernel(
    const float* __restrict__ k, const float* __restrict__ v,
    unsigned short* __restrict__ kf, unsigned short* __restrict__ vfr)
{
    const int id = blockIdx.x * 256 + threadIdx.x;
    const int KTOT = 4 * TILES * CHUNKS * 64;   // 131072 chunks of 8
    if (id < KTOT) {
        const int l = id & 63, c = (id >> 6) & 15, t = (id >> 10) & 31, b = id >> 15;
        const int row = t * BN + (c >> 1) * 16 + (l & 15);
        const int dd  = (c & 1) * 32 + (l >> 4) * 8;
        const float* src = k + ((size_t)b * S + row) * D + dd;
        float4 f0 = *(const float4*)src;
        float4 f1 = *(const float4*)(src + 4);
        s16x8 o = { (short)f2h(f0.x), (short)f2h(f0.y), (short)f2h(f0.z), (short)f2h(f0.w),
                    (short)f2h(f1.x), (short)f2h(f1.y), (short)f2h(f1.z), (short)f2h(f1.w) };
        *(s16x8*)(kf + (size_t)id * 8) = o;
    } else {
        const int vid = id - KTOT;
        const int l = vid & 63, c2 = (vid >> 6) & 15, t = (vid >> 10) & 31, b = vid >> 15;
        const int kk0 = t * BN + (c2 >> 2) * 32 + (l >> 4) * 8;
        const int dc  = (c2 & 3) * 16 + (l & 15);
        const float* src = v + ((size_t)b * S + kk0) * D + dc;
        s16x8 o;
        #pragma unroll
        for (int j = 0; j < 8; ++j) o[j] = (short)f2bf(src[(size_t)j * D]);
        *(s16x8*)(vfr + (size_t)vid * 8) = o;
    }
}

// ---------------- main kernel ----------------
__global__ __launch_bounds__(512) void attn_main(
    const float* __restrict__ q, const unsigned short* __restrict__ kf,
    const unsigned short* __restrict__ vfr, float* __restrict__ out)
{
    __shared__ unsigned short Kbuf[2][CHUNKS * 64 * 8];   // fp16 bits, 2x16KB
    __shared__ unsigned short Vbuf[2][CHUNKS * 64 * 8];   // bf16 bits, 2x16KB
    __shared__ unsigned short Pm[BQ][136];                // P[m][kk], pad->2-way-free

    const int tid  = threadIdx.x;
    const int lane = tid & 63;
    const int w    = tid >> 6;      // 0..7
    const int quad = lane >> 4;
    const int tq   = lane & 15;
    // GEMM1 roles: 4 kk-supertiles x 2 m-supertiles
    const int ksup = w & 3, msup = w >> 2;
    // GEMM2 roles: 2 m x 2 d x 2 contraction-halves
    const int h = w & 1, dq = (w >> 1) & 1, mq = w >> 2;

    const int b  = blockIdx.y;
    const int q0 = blockIdx.x * BQ;
    const unsigned short* kfb = kf  + (size_t)b * TILE_STRIDE;
    const unsigned short* vfb = vfr + (size_t)b * TILE_STRIDE;
    float* ob = out + (size_t)b * S * D;

    // ---- Q fragments, fp16, register-resident (B-frag: B[k=quad*8+j][n=tq]) ----
    h16x8 qf[2][2];   // [msub][ks]
    #pragma unroll
    for (int msub = 0; msub < 2; ++msub)
        #pragma unroll
        for (int ks = 0; ks < 2; ++ks) {
            const float* src = q + ((size_t)b * S + q0 + msup * 32 + msub * 16 + tq) * D
                             + ks * 32 + quad * 8;
            float4 f0 = *(const float4*)src;
            float4 f1 = *(const float4*)(src + 4);
            h16x8 qv = { (_Float16)f0.x, (_Float16)f0.y, (_Float16)f0.z, (_Float16)f0.w,
                         (_Float16)f1.x, (_Float16)f1.y, (_Float16)f1.z, (_Float16)f1.w };
            qf[msub][ks] = qv;
        }

    fx4 oacc[2][2] = {};   // [msub][dsub]

    auto issue_tile = [&](int tt, int bi) {
        #pragma unroll
        for (int ii = 0; ii < 2; ++ii) {
            const int c = w + ii * 8;
            const size_t goff = ((size_t)(tt * CHUNKS + c) * 64 + lane) * 8;
            __builtin_amdgcn_global_load_lds(
                (const __attribute__((address_space(1))) unsigned int*)(kfb + goff),
                (__attribute__((address_space(3))) unsigned int*)&Kbuf[bi][(c * 64 + lane) * 8],
                16, 0, 0);
            __builtin_amdgcn_global_load_lds(
                (const __attribute__((address_space(1))) unsigned int*)(vfb + goff),
                (__attribute__((address_space(3))) unsigned int*)&Vbuf[bi][(c * 64 + lane) * 8],
                16, 0, 0);
        }
    };

    issue_tile(0, 0);

    for (int t = 0; t < TILES; ++t) {
        const int cur = t & 1;
        __syncthreads();                 // drains DMA(t) (vmcnt) + frees Pm/bufs
        issue_tile((t + 1) & (TILES - 1), cur ^ 1);   // in flight all iteration

        // ---- GEMM1 (fp16): S^T supertile [32 kk x 32 m], contraction d=64 ----
        fx4 sacc[2][2] = {};   // [kks][msub]
        #pragma unroll
        for (int ks = 0; ks < 2; ++ks)
            #pragma unroll
            for (int kks = 0; kks < 2; ++kks) {
                const int c = (ksup * 2 + kks) * 2 + ks;
                h16x8 a = *(const h16x8*)&Kbuf[cur][(c * 64 + lane) * 8];
                #pragma unroll
                for (int msub = 0; msub < 2; ++msub)
                    sacc[kks][msub] = __builtin_amdgcn_mfma_f32_16x16x32_f16(
                        a, qf[msub][ks], sacc[kks][msub], 0, 0, 0);
            }

        // ---- P = exp(S^T) -> bf16 -> Pm[m][kk] (b64, 4 consecutive kk) ----
        #pragma unroll
        for (int kks = 0; kks < 2; ++kks)
            #pragma unroll
            for (int msub = 0; msub < 2; ++msub) {
                s16x4 pp = { (short)f2bf(__expf(sacc[kks][msub][0])),
                             (short)f2bf(__expf(sacc[kks][msub][1])),
                             (short)f2bf(__expf(sacc[kks][msub][2])),
                             (short)f2bf(__expf(sacc[kks][msub][3])) };
                *(s16x4*)&Pm[msup * 32 + msub * 16 + tq]
                            [ksup * 32 + kks * 16 + (quad << 2)] = pp;
            }

        // ---- mid barrier: LDS-only wait, do NOT drain in-flight DMA ----
        __asm__ volatile("" ::: "memory");
        __builtin_amdgcn_s_waitcnt(0xC07F);   // lgkmcnt(0), vmcnt/exp untouched
        __builtin_amdgcn_s_barrier();
        __asm__ volatile("" ::: "memory");

        // ---- GEMM2 (bf16): O[mq*32..][dq*32..] += P * V over kk half h ----
        #pragma unroll
        for (int i = 0; i < 2; ++i) {
            const int ks2 = h * 2 + i;
            s16x8 bfr[2];
            #pragma unroll
            for (int dsub = 0; dsub < 2; ++dsub)
                bfr[dsub] = *(const s16x8*)&Vbuf[cur]
                                [((ks2 * 4 + dq * 2 + dsub) * 64 + lane) * 8];
            #pragma unroll
            for (int msub = 0; msub < 2; ++msub) {
                s16x8 afr = *(const s16x8*)&Pm[mq * 32 + msub * 16 + tq]
                                              [ks2 * 32 + (quad << 3)];
                #pragma unroll
                for (int dsub = 0; dsub < 2; ++dsub)
                    oacc[msub][dsub] = __builtin_amdgcn_mfma_f32_16x16x32_bf16(
                        afr, bfr[dsub], oacc[msub][dsub], 0, 0, 0);
            }
        }
    }

    // ---- epilogue: reduce the two contraction-halves, store fp32 ----
    __syncthreads();
    fx4* red = (fx4*)&Kbuf[0][0];   // 16KB scratch
    const int p = w >> 1;           // pair id (mq,dq)
    if (h == 1) {
        #pragma unroll
        for (int msub = 0; msub < 2; ++msub)
            #pragma unroll
            for (int dsub = 0; dsub < 2; ++dsub)
                red[p * 256 + lane * 4 + msub * 2 + dsub] = oacc[msub][dsub];
    }
    __syncthreads();
    if (h == 0) {
        #pragma unroll
        for (int msub = 0; msub < 2; ++msub)
            #pragma unroll
            for (int dsub = 0; dsub < 2; ++dsub) {
                fx4 val = oacc[msub][dsub] + red[p * 256 + lane * 4 + msub * 2 + dsub];
                #pragma unroll
                for (int r = 0; r < 4; ++r)
                    ob[(size_t)(q0 + mq * 32 + msub * 16 + quad * 4 + r) * D
                       + dq * 32 + dsub * 16 + tq] = val[r];
            }
    }
}

// ---------------- fallback (round-2 kernel, used only if ws too small) ------
__global__ __launch_bounds__(1024) void attn_fallback(
    const float* __restrict__ q, const float* __restrict__ k,
    const float* __restrict__ v, float* __restrict__ out)
{
    __shared__ unsigned short Kh[64][72];
    __shared__ unsigned short Kl[64][72];
    __shared__ unsigned short Vt[64][68];
    __shared__ unsigned short Pf[64][72];

    const int tid = threadIdx.x, lane = tid & 63, wave = tid >> 6;
    const int quad = lane >> 4, tq = lane & 15;
    const int kkb = wave & 3, mba = wave >> 2;
    const int b = blockIdx.y, q0 = blockIdx.x * 64;
    const float* qb = q + (size_t)b * S * D;
    const float* kb = k + (size_t)b * S * D;
    const float* vb = v + (size_t)b * S * D;
    float* ob = out + (size_t)b * S * D;

    s16x8 qh[2], ql[2];
    {
        const float* qrow = qb + (size_t)(q0 + mba * 16 + tq) * D;
        #pragma unroll
        for (int ks = 0; ks < 2; ++ks) {
            const float* src = qrow + ks * 32 + quad * 8;
            float4 f0 = *(const float4*)src;
            float4 f1 = *(const float4*)(src + 4);
            float f[8] = {f0.x, f0.y, f0.z, f0.w, f1.x, f1.y, f1.z, f1.w};
            #pragma unroll
            for (int j = 0; j < 8; ++j) {
                unsigned short hh = f2bf(f[j]);
                qh[ks][j] = (short)hh;
                ql[ks][j] = (short)f2bf(f[j] - bf2f(hh));
            }
        }
    }
    fx4 oacc = {0.f, 0.f, 0.f, 0.f};
    const int krow = tid >> 4, kc4 = (tid & 15) << 2;
    const int vd = tid & 63, vk = (tid >> 6) << 2;

    for (int t = 0; t < S / 64; ++t) {
        __syncthreads();
        const float* kt = kb + (size_t)(t * 64 + krow) * D;
        const float* vt = vb + (size_t)(t * 64 + vk) * D;
        {
            float4 kv = *(const float4*)(kt + kc4);
            unsigned short h0 = f2bf(kv.x), h1 = f2bf(kv.y), h2 = f2bf(kv.z), h3 = f2bf(kv.w);
            s16x4 a = {(short)h0, (short)h1, (short)h2, (short)h3};
            s16x4 l4 = {(short)f2bf(kv.x - bf2f(h0)), (short)f2bf(kv.y - bf2f(h1)),
                        (short)f2bf(kv.z - bf2f(h2)), (short)f2bf(kv.w - bf2f(h3))};
            *(s16x4*)&Kh[krow][kc4] = a;
            *(s16x4*)&Kl[krow][kc4] = l4;
            const float* vs = vt + vd;
            s16x4 vv = {(short)f2bf(vs[0]), (short)f2bf(vs[D]),
                        (short)f2bf(vs[2 * D]), (short)f2bf(vs[3 * D])};
            *(s16x4*)&Vt[vd][vk] = vv;
        }
        __syncthreads();
        fx4 sacc = {0.f, 0.f, 0.f, 0.f};
        #pragma unroll
        for (int ks = 0; ks < 2; ++ks) {
            s16x8 kah = *(const s16x8*)&Kh[kkb * 16 + tq][ks * 32 + quad * 8];
            s16x8 kal = *(const s16x8*)&Kl[kkb * 16 + tq][ks * 32 + quad * 8];
            sacc = __builtin_amdgcn_mfma_f32_16x16x32_bf16(kah, qh[ks], sacc, 0, 0, 0);
            sacc = __builtin_amdgcn_mfma_f32_16x16x32_bf16(kah, ql[ks], sacc, 0, 0, 0);
            sacc = __builtin_amdgcn_mfma_f32_16x16x32_bf16(kal, qh[ks], sacc, 0, 0, 0);
        }
        s16x4 pp = {(short)f2bf(__expf(sacc[0])), (short)f2bf(__expf(sacc[1])),
                    (short)f2bf(__expf(sacc[2])), (short)f2bf(__expf(sacc[3]))};
        *(s16x4*)&Pf[mba * 16 + tq][kkb * 16 + (quad << 2)] = pp;
        __syncthreads();
        #pragma unroll
        for (int ks = 0; ks < 2; ++ks) {
            s16x8 pa = *(const s16x8*)&Pf[mba * 16 + tq][ks * 32 + quad * 8];
            const unsigned short* vr = &Vt[kkb * 16 + tq][ks * 32 + quad * 8];
            s16x4 va = *(const s16x4*)vr;
            s16x4 vb2 = *(const s16x4*)(vr + 4);
            s16x8 vfull = __builtin_shufflevector(va, vb2, 0, 1, 2, 3, 4, 5, 6, 7);
            oacc = __builtin_amdgcn_mfma_f32_16x16x32_bf16(pa, vfull, oacc, 0, 0, 0);
        }
    }
    #pragma unroll
    for (int r = 0; r < 4; ++r)
        ob[(size_t)(q0 + mba * 16 + quad * 4 + r) * D + kkb * 16 + tq] = oacc[r];
}

extern "C" void kernel_launch(void* const* d_in, const int* in_sizes, int n_in,
                              void* d_out, int out_size, void* d_ws, size_t ws_size,
                              hipStream_t stream) {
    const float* q = (const float*)d_in[0];
    const float* k = (const float*)d_in[1];
    const float* v = (const float*)d_in[2];
    float* out = (float*)d_out;
    const int nbatch = in_sizes[0] / (S * D);   // 4

    const size_t need = (size_t)nbatch * S * D * 2 * 2;   // K fp16 + V bf16 = 4MB
    if (nbatch == 4 && ws_size >= need && d_ws != nullptr) {
        unsigned short* kf  = (unsigned short*)d_ws;
        unsigned short* vfr = kf + (size_t)nbatch * S * D;
        const int total = 2 * nbatch * TILES * CHUNKS * 64;   // 262144
        prep_kernel<<<total / 256, 256, 0, stream>>>(k, v, kf, vfr);
        dim3 grid(S / BQ, nbatch);
        attn_main<<<grid, 512, 0, stream>>>(q, kf, vfr, out);
    } else {
        dim3 grid(S / 64, nbatch);
        attn_fallback<<<grid, 1024, 0, stream>>>(q, k, v, out);
    }
}

// Round 4
// 98.010 us; speedup vs baseline: 4.2377x; 1.0847x over previous
//
#include <hip/hip_runtime.h>

// out = exp(Q K^T) V, unnormalized. B=4, S=4096, D=64, fp32 in/out.
// Round 4: LDS-bandwidth-targeted rewrite.
//  * 32x32x16 MFMA both GEMMs (halves LDS bytes per FLOP vs 16x16x32).
//  * P stays in registers: Sc^T C-layout -> GEMM2 A-layout needs only a
//    lane^32 exchange (8 packed shfl_xor) -> no P LDS round-trip, and only
//    ONE barrier per K-tile iteration.
//  * Triple-buffered K/V tiles, depth-2 DMA prefetch, loop-top
//    s_waitcnt vmcnt(4) + raw s_barrier (tile t+1 stays in flight).
//  * Wave (of 8) owns (m-tile in {0,1}) x (kk-quarter in {0..3}); partial O
//    reduced across kk-quarters once at epilogue through LDS.
//  * prep: coalesced loads + LDS transpose -> K fp16 / V bf16 in exact
//    32x32x16 fragment order (A-frag for K, B-frag for V).

typedef short    s16x4 __attribute__((ext_vector_type(4)));
typedef short    s16x8 __attribute__((ext_vector_type(8)));
typedef _Float16 h16x8 __attribute__((ext_vector_type(8)));
typedef float    fx4   __attribute__((ext_vector_type(4)));
typedef float    fx16  __attribute__((ext_vector_type(16)));

constexpr int S = 4096, D = 64, BQ = 64, BN = 128;
constexpr int TILES = S / BN;                       // 32
constexpr int TILE_SHORTS  = 16 * 512;              // 16KB per array per tile
constexpr int BATCH_SHORTS = TILES * TILE_SHORTS;   // 262144

__device__ __forceinline__ unsigned short f2bf(float x) {
    unsigned u = __float_as_uint(x);
    u = (u + 0x7FFFu + ((u >> 16) & 1u)) >> 16;   // RNE
    return (unsigned short)u;
}
__device__ __forceinline__ float bf2f(unsigned short h) {
    return __uint_as_float(((unsigned)h) << 16);
}
__device__ __forceinline__ unsigned short f2h(float x) {
    union { _Float16 h; unsigned short s; } u;
    u.h = (_Float16)x;
    return u.s;
}

// -------- prep: K -> fp16 A-frag order, V -> bf16 B-frag order (32x32x16) ---
// K chunk c = kkq*4+ks : [lane][j] = K[t*128 + kkq*32 + (lane&31)][ks*16 + (lane>>5)*8 + j]
// V chunk c = ss*2+dt  : [lane][j] = V[t*128 + ss*16 + (lane>>5)*8 + j][dt*32 + (lane&31)]
__global__ __launch_bounds__(256) void prep2(
    const float* __restrict__ k, const float* __restrict__ v,
    unsigned short* __restrict__ kf, unsigned short* __restrict__ vf)
{
    __shared__ unsigned short tile[128 * 72];   // row stride 72 halves (pad)
    const int tid   = threadIdx.x;
    const int which = blockIdx.x & 1;           // 0 = K, 1 = V
    const int t     = (blockIdx.x >> 1) & 31;
    const int b     = blockIdx.x >> 6;
    const float* src = (which ? v : k) + ((size_t)b * S + t * BN) * D;

    #pragma unroll
    for (int i = 0; i < 8; ++i) {               // coalesced: 2048 float4s/block
        int f   = i * 256 + tid;
        int row = f >> 4;
        int c4  = (f & 15) << 2;
        float4 x = *(const float4*)(src + row * D + c4);
        s16x4 o;
        if (which) o = (s16x4){(short)f2bf(x.x), (short)f2bf(x.y),
                               (short)f2bf(x.z), (short)f2bf(x.w)};
        else       o = (s16x4){(short)f2h(x.x), (short)f2h(x.y),
                               (short)f2h(x.z), (short)f2h(x.w)};
        *(s16x4*)&tile[row * 72 + c4] = o;
    }
    __syncthreads();

    const int lane = tid & 63;
    unsigned short* dst = (which ? vf : kf) + (size_t)b * BATCH_SHORTS + t * TILE_SHORTS;
    #pragma unroll
    for (int i = 0; i < 4; ++i) {
        int c = (tid >> 6) * 4 + i;             // chunk 0..15
        s16x8 o;
        if (which == 0) {
            int row = (c >> 2) * 32 + (lane & 31);
            int dc  = (c & 3) * 16 + (lane >> 5) * 8;
            o = *(const s16x8*)&tile[row * 72 + dc];     // b128, aligned
        } else {
            int r0 = (c >> 1) * 16 + (lane >> 5) * 8;
            int dc = (c & 1) * 32 + (lane & 31);
            #pragma unroll
            for (int j = 0; j < 8; ++j) o[j] = (short)tile[(r0 + j) * 72 + dc];
        }
        *(s16x8*)(dst + c * 512 + lane * 8) = o;         // coalesced b128
    }
}

// ---------------- main ----------------
__global__ __launch_bounds__(512) void attn_main2(
    const float* __restrict__ q, const unsigned short* __restrict__ kf,
    const unsigned short* __restrict__ vf, float* __restrict__ out)
{
    __shared__ unsigned short smem[3 * 2 * TILE_SHORTS];   // 96KB: 3 x (K 16K | V 16K)

    const int tid = threadIdx.x, lane = tid & 63, w = tid >> 6;
    const int h = lane >> 5, m5 = lane & 31;
    const int mt = w & 1, kkq = w >> 1;         // m-tile, kk-quarter
    const int b = blockIdx.y, q0 = blockIdx.x * BQ;

    const unsigned short* kfb = kf + (size_t)b * BATCH_SHORTS;
    const unsigned short* vfb = vf + (size_t)b * BATCH_SHORTS;

    // Q B-frags fp16: B[k=h*8+j][n=m5] = Q[q0+mt*32+m5][ks*16+h*8+j]
    h16x8 qf[4];
    {
        const float* qrow = q + ((size_t)b * S + q0 + mt * 32 + m5) * D + h * 8;
        #pragma unroll
        for (int ks = 0; ks < 4; ++ks) {
            float4 a = *(const float4*)(qrow + ks * 16);
            float4 c = *(const float4*)(qrow + ks * 16 + 4);
            qf[ks] = (h16x8){(_Float16)a.x, (_Float16)a.y, (_Float16)a.z, (_Float16)a.w,
                             (_Float16)c.x, (_Float16)c.y, (_Float16)c.z, (_Float16)c.w};
        }
    }

    fx16 oacc[2] = {};   // [dt] O[mt*32.. , dt*32..], partial over kk-quarter

    auto issue = [&](int t, int bi) {
        unsigned short* base = &smem[bi * 2 * TILE_SHORTS];
        #pragma unroll
        for (int ii = 0; ii < 4; ++ii) {                 // ii<2: K, else V
            int c = (ii & 1) * 8 + w;                    // chunk 0..15
            const unsigned short* g = (ii < 2 ? kfb : vfb)
                + (size_t)t * TILE_SHORTS + c * 512 + lane * 8;
            unsigned short* l = base + (ii < 2 ? 0 : TILE_SHORTS) + c * 512 + lane * 8;
            __builtin_amdgcn_global_load_lds(
                (const __attribute__((address_space(1))) unsigned int*)g,
                (__attribute__((address_space(3))) unsigned int*)l, 16, 0, 0);
        }
    };

    issue(0, 0);
    issue(1, 1);

    for (int t = 0; t < TILES; ++t) {
        const int bi = t % 3;
        __asm__ volatile("" ::: "memory");
        __builtin_amdgcn_s_waitcnt(0x0F74);   // vmcnt(4): tile t landed; t+1 in flight
        __builtin_amdgcn_s_barrier();
        __asm__ volatile("" ::: "memory");
        issue((t + 2) & (TILES - 1), (t + 2) % 3);

        const unsigned short* kb = &smem[bi * 2 * TILE_SHORTS];
        const unsigned short* vb = kb + TILE_SHORTS;

        // ---- GEMM1 (fp16 32x32x16): Sc^T[kk 32][m 32], contraction d=64 ----
        fx16 sa = {};
        #pragma unroll
        for (int ks = 0; ks < 4; ++ks) {
            h16x8 a = *(const h16x8*)(kb + (kkq * 4 + ks) * 512 + lane * 8);
            sa = __builtin_amdgcn_mfma_f32_32x32x16_f16(a, qf[ks], sa, 0, 0, 0);
        }

        // ---- P = exp(Sc^T) in regs; C-layout kk = (r&3)+8*(r>>2)+4h, m = m5.
        // Pack pairs (kk even,odd) as bf16x2; lane^32 swap supplies the
        // missing kk nibble; select per half -> GEMM2 A-frags (kk 0..15 / 16..31).
        unsigned p01[8], sw[8];
        #pragma unroll
        for (int r = 0; r < 8; ++r) {
            unsigned lo = f2bf(__expf(sa[2 * r]));
            unsigned hi = f2bf(__expf(sa[2 * r + 1]));
            p01[r] = lo | (hi << 16);
        }
        #pragma unroll
        for (int r = 0; r < 8; ++r) sw[r] = (unsigned)__shfl_xor((int)p01[r], 32, 64);

        union { unsigned u[4]; s16x8 v; } A1u, A2u;
        A1u.u[0] = h ? sw[2]  : p01[0];  A1u.u[1] = h ? sw[3]  : p01[1];
        A1u.u[2] = h ? p01[2] : sw[0];   A1u.u[3] = h ? p01[3] : sw[1];
        A2u.u[0] = h ? sw[6]  : p01[4];  A2u.u[1] = h ? sw[7]  : p01[5];
        A2u.u[2] = h ? p01[6] : sw[4];   A2u.u[3] = h ? p01[7] : sw[5];

        // ---- GEMM2 (bf16 32x32x16): O += P * V over this wave's 32 kk ----
        #pragma unroll
        for (int u = 0; u < 2; ++u) {
            s16x8 Au = u ? A2u.v : A1u.v;
            int ss = kkq * 2 + u;                        // global 16-kk step
            #pragma unroll
            for (int dt = 0; dt < 2; ++dt) {
                s16x8 vv = *(const s16x8*)(vb + (ss * 2 + dt) * 512 + lane * 8);
                oacc[dt] = __builtin_amdgcn_mfma_f32_32x32x16_bf16(Au, vv, oacc[dt], 0, 0, 0);
            }
        }
    }

    // ---- epilogue: reduce 4 kk-quarter partials per m-tile, store fp32 ----
    __syncthreads();                     // drains vmcnt(0) -> smem reusable
    float* scratch = (float*)smem;       // 48KB used of 96KB
    if (kkq > 0) {
        float* dst = scratch + (size_t)(mt * 3 + (kkq - 1)) * 2048;
        #pragma unroll
        for (int dt = 0; dt < 2; ++dt)
            #pragma unroll
            for (int r = 0; r < 16; ++r)
                dst[(dt * 16 + r) * 64 + lane] = oacc[dt][r];
    }
    __syncthreads();
    if (kkq == 0) {
        float* ob = out + (size_t)b * S * D;
        #pragma unroll
        for (int dt = 0; dt < 2; ++dt)
            #pragma unroll
            for (int r = 0; r < 16; ++r) {
                float val = oacc[dt][r];
                #pragma unroll
                for (int p = 0; p < 3; ++p)
                    val += scratch[(size_t)(mt * 3 + p) * 2048 + (dt * 16 + r) * 64 + lane];
                int row = q0 + mt * 32 + (r & 3) + 8 * (r >> 2) + 4 * h;
                ob[(size_t)row * D + dt * 32 + m5] = val;
            }
    }
}

// ---------------- fallback (known-good round-2 kernel) ----------------
__global__ __launch_bounds__(1024) void attn_fallback(
    const float* __restrict__ q, const float* __restrict__ k,
    const float* __restrict__ v, float* __restrict__ out)
{
    __shared__ unsigned short Kh[64][72];
    __shared__ unsigned short Kl[64][72];
    __shared__ unsigned short Vt[64][68];
    __shared__ unsigned short Pf[64][72];

    const int tid = threadIdx.x, lane = tid & 63, wave = tid >> 6;
    const int quad = lane >> 4, tq = lane & 15;
    const int kkb = wave & 3, mba = wave >> 2;
    const int b = blockIdx.y, q0 = blockIdx.x * 64;
    const float* qb = q + (size_t)b * S * D;
    const float* kb = k + (size_t)b * S * D;
    const float* vb = v + (size_t)b * S * D;
    float* ob = out + (size_t)b * S * D;

    s16x8 qh[2], ql[2];
    {
        const float* qrow = qb + (size_t)(q0 + mba * 16 + tq) * D;
        #pragma unroll
        for (int ks = 0; ks < 2; ++ks) {
            const float* src = qrow + ks * 32 + quad * 8;
            float4 f0 = *(const float4*)src;
            float4 f1 = *(const float4*)(src + 4);
            float f[8] = {f0.x, f0.y, f0.z, f0.w, f1.x, f1.y, f1.z, f1.w};
            #pragma unroll
            for (int j = 0; j < 8; ++j) {
                unsigned short hh = f2bf(f[j]);
                qh[ks][j] = (short)hh;
                ql[ks][j] = (short)f2bf(f[j] - bf2f(hh));
            }
        }
    }
    fx4 oacc = {0.f, 0.f, 0.f, 0.f};
    const int krow = tid >> 4, kc4 = (tid & 15) << 2;
    const int vd = tid & 63, vk = (tid >> 6) << 2;

    for (int t = 0; t < S / 64; ++t) {
        __syncthreads();
        const float* kt = kb + (size_t)(t * 64 + krow) * D;
        const float* vt = vb + (size_t)(t * 64 + vk) * D;
        {
            float4 kv = *(const float4*)(kt + kc4);
            unsigned short h0 = f2bf(kv.x), h1 = f2bf(kv.y), h2 = f2bf(kv.z), h3 = f2bf(kv.w);
            s16x4 a = {(short)h0, (short)h1, (short)h2, (short)h3};
            s16x4 l4 = {(short)f2bf(kv.x - bf2f(h0)), (short)f2bf(kv.y - bf2f(h1)),
                        (short)f2bf(kv.z - bf2f(h2)), (short)f2bf(kv.w - bf2f(h3))};
            *(s16x4*)&Kh[krow][kc4] = a;
            *(s16x4*)&Kl[krow][kc4] = l4;
            const float* vs = vt + vd;
            s16x4 vv = {(short)f2bf(vs[0]), (short)f2bf(vs[D]),
                        (short)f2bf(vs[2 * D]), (short)f2bf(vs[3 * D])};
            *(s16x4*)&Vt[vd][vk] = vv;
        }
        __syncthreads();
        fx4 sacc = {0.f, 0.f, 0.f, 0.f};
        #pragma unroll
        for (int ks = 0; ks < 2; ++ks) {
            s16x8 kah = *(const s16x8*)&Kh[kkb * 16 + tq][ks * 32 + quad * 8];
            s16x8 kal = *(const s16x8*)&Kl[kkb * 16 + tq][ks * 32 + quad * 8];
            sacc = __builtin_amdgcn_mfma_f32_16x16x32_bf16(kah, qh[ks], sacc, 0, 0, 0);
            sacc = __builtin_amdgcn_mfma_f32_16x16x32_bf16(kah, ql[ks], sacc, 0, 0, 0);
            sacc = __builtin_amdgcn_mfma_f32_16x16x32_bf16(kal, qh[ks], sacc, 0, 0, 0);
        }
        s16x4 pp = {(short)f2bf(__expf(sacc[0])), (short)f2bf(__expf(sacc[1])),
                    (short)f2bf(__expf(sacc[2])), (short)f2bf(__expf(sacc[3]))};
        *(s16x4*)&Pf[mba * 16 + tq][kkb * 16 + (quad << 2)] = pp;
        __syncthreads();
        #pragma unroll
        for (int ks = 0; ks < 2; ++ks) {
            s16x8 pa = *(const s16x8*)&Pf[mba * 16 + tq][ks * 32 + quad * 8];
            const unsigned short* vr = &Vt[kkb * 16 + tq][ks * 32 + quad * 8];
            s16x4 va = *(const s16x4*)vr;
            s16x4 vb2 = *(const s16x4*)(vr + 4);
            s16x8 vfull = __builtin_shufflevector(va, vb2, 0, 1, 2, 3, 4, 5, 6, 7);
            oacc = __builtin_amdgcn_mfma_f32_16x16x32_bf16(pa, vfull, oacc, 0, 0, 0);
        }
    }
    #pragma unroll
    for (int r = 0; r < 4; ++r)
        ob[(size_t)(q0 + mba * 16 + quad * 4 + r) * D + kkb * 16 + tq] = oacc[r];
}

extern "C" void kernel_launch(void* const* d_in, const int* in_sizes, int n_in,
                              void* d_out, int out_size, void* d_ws, size_t ws_size,
                              hipStream_t stream) {
    const float* q = (const float*)d_in[0];
    const float* k = (const float*)d_in[1];
    const float* v = (const float*)d_in[2];
    float* out = (float*)d_out;
    const int nbatch = in_sizes[0] / (S * D);   // 4

    const size_t need = (size_t)nbatch * S * D * 2 * 2;   // K fp16 + V bf16 = 4MB
    if (nbatch == 4 && ws_size >= need && d_ws != nullptr) {
        unsigned short* kf = (unsigned short*)d_ws;
        unsigned short* vf = kf + (size_t)nbatch * S * D;
        prep2<<<nbatch * TILES * 2, 256, 0, stream>>>(k, v, kf, vf);
        dim3 grid(S / BQ, nbatch);
        attn_main2<<<grid, 512, 0, stream>>>(q, kf, vf, out);
    } else {
        dim3 grid(S / 64, nbatch);
        attn_fallback<<<grid, 1024, 0, stream>>>(q, k, v, out);
    }
}

// Round 5
// 96.989 us; speedup vs baseline: 4.2823x; 1.0105x over previous
//
#include <hip/hip_runtime.h>
#include <hip/hip_bf16.h>

// out = exp(Q K^T) V, unnormalized. B=4, S=4096, D=64, fp32 in/out.
// Round 5: occupancy-targeted. Round-3/4 main kernels both pinned at ~43us
// with 2 waves/SIMD (1 block/CU) -> latency-bound on ds_read->MFMA->exp
// chains. Fix: kk-split grid (2 halves) -> 512 blocks = 2 blocks/CU,
// 64KB LDS double-buffer per block -> 16 waves/CU = 4 waves/SIMD, plus
// cross-block barrier overlap. Partial O per kk-half into ws, tiny reduce
// kernel sums into d_out. Inner structure unchanged from round 4
// (32x32x16 MFMA, P in registers via lane^32 exchange, 1 barrier/iter,
// DMA issued after barrier into the buffer freed by that barrier).

typedef short    s16x4 __attribute__((ext_vector_type(4)));
typedef short    s16x8 __attribute__((ext_vector_type(8)));
typedef _Float16 h16x8 __attribute__((ext_vector_type(8)));
typedef float    fx4   __attribute__((ext_vector_type(4)));
typedef float    fx16  __attribute__((ext_vector_type(16)));

constexpr int S = 4096, D = 64, BQ = 64, BN = 128;
constexpr int TILES = S / BN;                       // 32
constexpr int HALF_TILES = TILES / 2;               // 16 per kk-half
constexpr int TILE_SHORTS  = 16 * 512;              // 16KB per array per tile
constexpr int BATCH_SHORTS = TILES * TILE_SHORTS;   // 262144

__device__ __forceinline__ unsigned short f2bf(float x) {
    unsigned u = __float_as_uint(x);
    u = (u + 0x7FFFu + ((u >> 16) & 1u)) >> 16;   // RNE
    return (unsigned short)u;
}
__device__ __forceinline__ float bf2f(unsigned short h) {
    return __uint_as_float(((unsigned)h) << 16);
}
__device__ __forceinline__ unsigned short f2h(float x) {
    union { _Float16 h; unsigned short s; } u;
    u.h = (_Float16)x;
    return u.s;
}
__device__ __forceinline__ unsigned pack_bf16(float lo, float hi) {
    __hip_bfloat162 r = __float22bfloat162_rn(make_float2(lo, hi));
    union { __hip_bfloat162 b; unsigned u; } c;
    c.b = r;
    return c.u;
}

// -------- prep: K -> fp16 A-frag order, V -> bf16 B-frag order (32x32x16) ---
// K chunk c = kkq*4+ks : [lane][j] = K[t*128 + kkq*32 + (lane&31)][ks*16 + (lane>>5)*8 + j]
// V chunk c = ss*2+dt  : [lane][j] = V[t*128 + ss*16 + (lane>>5)*8 + j][dt*32 + (lane&31)]
__global__ __launch_bounds__(256) void prep2(
    const float* __restrict__ k, const float* __restrict__ v,
    unsigned short* __restrict__ kf, unsigned short* __restrict__ vf)
{
    __shared__ unsigned short tile[128 * 72];   // row stride 72 halves (pad)
    const int tid   = threadIdx.x;
    const int which = blockIdx.x & 1;           // 0 = K, 1 = V
    const int t     = (blockIdx.x >> 1) & 31;
    const int b     = blockIdx.x >> 6;
    const float* src = (which ? v : k) + ((size_t)b * S + t * BN) * D;

    #pragma unroll
    for (int i = 0; i < 8; ++i) {               // coalesced: 2048 float4s/block
        int f   = i * 256 + tid;
        int row = f >> 4;
        int c4  = (f & 15) << 2;
        float4 x = *(const float4*)(src + row * D + c4);
        s16x4 o;
        if (which) o = (s16x4){(short)f2bf(x.x), (short)f2bf(x.y),
                               (short)f2bf(x.z), (short)f2bf(x.w)};
        else       o = (s16x4){(short)f2h(x.x), (short)f2h(x.y),
                               (short)f2h(x.z), (short)f2h(x.w)};
        *(s16x4*)&tile[row * 72 + c4] = o;
    }
    __syncthreads();

    const int lane = tid & 63;
    unsigned short* dst = (which ? vf : kf) + (size_t)b * BATCH_SHORTS + t * TILE_SHORTS;
    #pragma unroll
    for (int i = 0; i < 4; ++i) {
        int c = (tid >> 6) * 4 + i;             // chunk 0..15
        s16x8 o;
        if (which == 0) {
            int row = (c >> 2) * 32 + (lane & 31);
            int dc  = (c & 3) * 16 + (lane >> 5) * 8;
            o = *(const s16x8*)&tile[row * 72 + dc];     // b128, aligned
        } else {
            int r0 = (c >> 1) * 16 + (lane >> 5) * 8;
            int dc = (c & 1) * 32 + (lane & 31);
            #pragma unroll
            for (int j = 0; j < 8; ++j) o[j] = (short)tile[(r0 + j) * 72 + dc];
        }
        *(s16x8*)(dst + c * 512 + lane * 8) = o;         // coalesced b128
    }
}

// ---------------- main: one kk-half per block ----------------
__global__ __launch_bounds__(512, 4) void attn_main3(
    const float* __restrict__ q, const unsigned short* __restrict__ kf,
    const unsigned short* __restrict__ vf, float* __restrict__ partial)
{
    __shared__ unsigned short smem[2 * 2 * TILE_SHORTS];   // 64KB: 2 x (K 16K | V 16K)

    const int tid = threadIdx.x, lane = tid & 63, w = tid >> 6;
    const int h = lane >> 5, m5 = lane & 31;
    const int mt = w & 1, kkq = w >> 1;         // m-tile, kk-quarter (of the tile)
    const int b = blockIdx.y, q0 = blockIdx.x * BQ;
    const int kh = blockIdx.z;                  // kk-half 0/1
    const int t0 = kh * HALF_TILES;

    const unsigned short* kfb = kf + (size_t)b * BATCH_SHORTS;
    const unsigned short* vfb = vf + (size_t)b * BATCH_SHORTS;

    // Q B-frags fp16: B[k=h*8+j][n=m5] = Q[q0+mt*32+m5][ks*16+h*8+j]
    h16x8 qf[4];
    {
        const float* qrow = q + ((size_t)b * S + q0 + mt * 32 + m5) * D + h * 8;
        #pragma unroll
        for (int ks = 0; ks < 4; ++ks) {
            float4 a = *(const float4*)(qrow + ks * 16);
            float4 c = *(const float4*)(qrow + ks * 16 + 4);
            qf[ks] = (h16x8){(_Float16)a.x, (_Float16)a.y, (_Float16)a.z, (_Float16)a.w,
                             (_Float16)c.x, (_Float16)c.y, (_Float16)c.z, (_Float16)c.w};
        }
    }

    fx16 oacc[2] = {};   // [dt] O[mt*32.., dt*32..], partial over kk-quarter+half

    auto issue = [&](int t, int bi) {
        unsigned short* base = &smem[bi * 2 * TILE_SHORTS];
        #pragma unroll
        for (int ii = 0; ii < 4; ++ii) {                 // ii<2: K, else V
            int c = (ii & 1) * 8 + w;                    // chunk 0..15
            const unsigned short* g = (ii < 2 ? kfb : vfb)
                + (size_t)t * TILE_SHORTS + c * 512 + lane * 8;
            unsigned short* l = base + (ii < 2 ? 0 : TILE_SHORTS) + c * 512 + lane * 8;
            __builtin_amdgcn_global_load_lds(
                (const __attribute__((address_space(1))) unsigned int*)g,
                (__attribute__((address_space(3))) unsigned int*)l, 16, 0, 0);
        }
    };

    issue(t0, 0);

    for (int i = 0; i < HALF_TILES; ++i) {
        const int bi = i & 1;
        // Wave's own 4 loads of tile i (issued one full iteration ago) landed;
        // barrier also proves all waves finished reading buffer bi^1 -> safe
        // to DMA tile i+1 into it. One barrier per iteration total.
        __asm__ volatile("" ::: "memory");
        __builtin_amdgcn_s_waitcnt(0x0F70);   // vmcnt(0), lgkm/exp untouched
        __builtin_amdgcn_s_barrier();
        __asm__ volatile("" ::: "memory");
        if (i + 1 < HALF_TILES) issue(t0 + i + 1, bi ^ 1);

        const unsigned short* kb = &smem[bi * 2 * TILE_SHORTS];
        const unsigned short* vb = kb + TILE_SHORTS;

        // ---- GEMM1 (fp16 32x32x16): Sc^T[kk 32][m 32], contraction d=64 ----
        fx16 sa = {};
        #pragma unroll
        for (int ks = 0; ks < 4; ++ks) {
            h16x8 a = *(const h16x8*)(kb + (kkq * 4 + ks) * 512 + lane * 8);
            sa = __builtin_amdgcn_mfma_f32_32x32x16_f16(a, qf[ks], sa, 0, 0, 0);
        }

        // ---- P = exp(Sc^T) in regs; C-layout kk = (r&3)+8*(r>>2)+4h, m = m5.
        // Pack (kk even,odd) pairs as bf16x2; lane^32 swap supplies the
        // missing kk nibble; select per half -> GEMM2 A-frags.
        unsigned p01[8], sw[8];
        #pragma unroll
        for (int r = 0; r < 8; ++r)
            p01[r] = pack_bf16(__expf(sa[2 * r]), __expf(sa[2 * r + 1]));
        #pragma unroll
        for (int r = 0; r < 8; ++r) sw[r] = (unsigned)__shfl_xor((int)p01[r], 32, 64);

        union { unsigned u[4]; s16x8 v; } A1u, A2u;
        A1u.u[0] = h ? sw[2]  : p01[0];  A1u.u[1] = h ? sw[3]  : p01[1];
        A1u.u[2] = h ? p01[2] : sw[0];   A1u.u[3] = h ? p01[3] : sw[1];
        A2u.u[0] = h ? sw[6]  : p01[4];  A2u.u[1] = h ? sw[7]  : p01[5];
        A2u.u[2] = h ? p01[6] : sw[4];   A2u.u[3] = h ? p01[7] : sw[5];

        // ---- GEMM2 (bf16 32x32x16): O += P * V over this wave's 32 kk ----
        #pragma unroll
        for (int u = 0; u < 2; ++u) {
            s16x8 Au = u ? A2u.v : A1u.v;
            int ss = kkq * 2 + u;                        // 16-kk step in tile
            #pragma unroll
            for (int dt = 0; dt < 2; ++dt) {
                s16x8 vv = *(const s16x8*)(vb + (ss * 2 + dt) * 512 + lane * 8);
                oacc[dt] = __builtin_amdgcn_mfma_f32_32x32x16_bf16(Au, vv, oacc[dt], 0, 0, 0);
            }
        }
    }

    // ---- epilogue: reduce 4 kk-quarter partials per m-tile -> ws partial ----
    __syncthreads();                     // all DMA drained (vmcnt(0) at top of last iter)
    float* scratch = (float*)smem;       // 48KB used of 64KB
    if (kkq > 0) {
        float* dst = scratch + (size_t)(mt * 3 + (kkq - 1)) * 2048;
        #pragma unroll
        for (int dt = 0; dt < 2; ++dt)
            #pragma unroll
            for (int r = 0; r < 16; ++r)
                dst[(dt * 16 + r) * 64 + lane] = oacc[dt][r];
    }
    __syncthreads();
    if (kkq == 0) {
        float* pout = partial + ((size_t)kh * gridDim.y + b) * S * D;
        #pragma unroll
        for (int dt = 0; dt < 2; ++dt)
            #pragma unroll
            for (int r = 0; r < 16; ++r) {
                float val = oacc[dt][r];
                #pragma unroll
                for (int p = 0; p < 3; ++p)
                    val += scratch[(size_t)(mt * 3 + p) * 2048 + (dt * 16 + r) * 64 + lane];
                int row = q0 + mt * 32 + (r & 3) + 8 * (r >> 2) + 4 * h;
                pout[(size_t)row * D + dt * 32 + m5] = val;
            }
    }
}

// ---------------- final reduce: out = partial[0] + partial[1] ----------------
__global__ __launch_bounds__(256) void reduce_out(
    const float4* __restrict__ p0, const float4* __restrict__ p1,
    float4* __restrict__ o, int n4)
{
    int i = blockIdx.x * 256 + threadIdx.x;
    if (i < n4) {
        float4 a = p0[i], b = p1[i];
        o[i] = make_float4(a.x + b.x, a.y + b.y, a.z + b.z, a.w + b.w);
    }
}

// ---------------- fallback (known-good round-2 kernel) ----------------
__global__ __launch_bounds__(1024) void attn_fallback(
    const float* __restrict__ q, const float* __restrict__ k,
    const float* __restrict__ v, float* __restrict__ out)
{
    __shared__ unsigned short Kh[64][72];
    __shared__ unsigned short Kl[64][72];
    __shared__ unsigned short Vt[64][68];
    __shared__ unsigned short Pf[64][72];

    const int tid = threadIdx.x, lane = tid & 63, wave = tid >> 6;
    const int quad = lane >> 4, tq = lane & 15;
    const int kkb = wave & 3, mba = wave >> 2;
    const int b = blockIdx.y, q0 = blockIdx.x * 64;
    const float* qb = q + (size_t)b * S * D;
    const float* kb = k + (size_t)b * S * D;
    const float* vb = v + (size_t)b * S * D;
    float* ob = out + (size_t)b * S * D;

    s16x8 qh[2], ql[2];
    {
        const float* qrow = qb + (size_t)(q0 + mba * 16 + tq) * D;
        #pragma unroll
        for (int ks = 0; ks < 2; ++ks) {
            const float* src = qrow + ks * 32 + quad * 8;
            float4 f0 = *(const float4*)src;
            float4 f1 = *(const float4*)(src + 4);
            float f[8] = {f0.x, f0.y, f0.z, f0.w, f1.x, f1.y, f1.z, f1.w};
            #pragma unroll
            for (int j = 0; j < 8; ++j) {
                unsigned short hh = f2bf(f[j]);
                qh[ks][j] = (short)hh;
                ql[ks][j] = (short)f2bf(f[j] - bf2f(hh));
            }
        }
    }
    fx4 oacc = {0.f, 0.f, 0.f, 0.f};
    const int krow = tid >> 4, kc4 = (tid & 15) << 2;
    const int vd = tid & 63, vk = (tid >> 6) << 2;

    for (int t = 0; t < S / 64; ++t) {
        __syncthreads();
        const float* kt = kb + (size_t)(t * 64 + krow) * D;
        const float* vt = vb + (size_t)(t * 64 + vk) * D;
        {
            float4 kv = *(const float4*)(kt + kc4);
            unsigned short h0 = f2bf(kv.x), h1 = f2bf(kv.y), h2 = f2bf(kv.z), h3 = f2bf(kv.w);
            s16x4 a = {(short)h0, (short)h1, (short)h2, (short)h3};
            s16x4 l4 = {(short)f2bf(kv.x - bf2f(h0)), (short)f2bf(kv.y - bf2f(h1)),
                        (short)f2bf(kv.z - bf2f(h2)), (short)f2bf(kv.w - bf2f(h3))};
            *(s16x4*)&Kh[krow][kc4] = a;
            *(s16x4*)&Kl[krow][kc4] = l4;
            const float* vs = vt + vd;
            s16x4 vv = {(short)f2bf(vs[0]), (short)f2bf(vs[D]),
                        (short)f2bf(vs[2 * D]), (short)f2bf(vs[3 * D])};
            *(s16x4*)&Vt[vd][vk] = vv;
        }
        __syncthreads();
        fx4 sacc = {0.f, 0.f, 0.f, 0.f};
        #pragma unroll
        for (int ks = 0; ks < 2; ++ks) {
            s16x8 kah = *(const s16x8*)&Kh[kkb * 16 + tq][ks * 32 + quad * 8];
            s16x8 kal = *(const s16x8*)&Kl[kkb * 16 + tq][ks * 32 + quad * 8];
            sacc = __builtin_amdgcn_mfma_f32_16x16x32_bf16(kah, qh[ks], sacc, 0, 0, 0);
            sacc = __builtin_amdgcn_mfma_f32_16x16x32_bf16(kah, ql[ks], sacc, 0, 0, 0);
            sacc = __builtin_amdgcn_mfma_f32_16x16x32_bf16(kal, qh[ks], sacc, 0, 0, 0);
        }
        s16x4 pp = {(short)f2bf(__expf(sacc[0])), (short)f2bf(__expf(sacc[1])),
                    (short)f2bf(__expf(sacc[2])), (short)f2bf(__expf(sacc[3]))};
        *(s16x4*)&Pf[mba * 16 + tq][kkb * 16 + (quad << 2)] = pp;
        __syncthreads();
        #pragma unroll
        for (int ks = 0; ks < 2; ++ks) {
            s16x8 pa = *(const s16x8*)&Pf[mba * 16 + tq][ks * 32 + quad * 8];
            const unsigned short* vr = &Vt[kkb * 16 + tq][ks * 32 + quad * 8];
            s16x4 va = *(const s16x4*)vr;
            s16x4 vb2 = *(const s16x4*)(vr + 4);
            s16x8 vfull = __builtin_shufflevector(va, vb2, 0, 1, 2, 3, 4, 5, 6, 7);
            oacc = __builtin_amdgcn_mfma_f32_16x16x32_bf16(pa, vfull, oacc, 0, 0, 0);
        }
    }
    #pragma unroll
    for (int r = 0; r < 4; ++r)
        ob[(size_t)(q0 + mba * 16 + quad * 4 + r) * D + kkb * 16 + tq] = oacc[r];
}

extern "C" void kernel_launch(void* const* d_in, const int* in_sizes, int n_in,
                              void* d_out, int out_size, void* d_ws, size_t ws_size,
                              hipStream_t stream) {
    const float* q = (const float*)d_in[0];
    const float* k = (const float*)d_in[1];
    const float* v = (const float*)d_in[2];
    float* out = (float*)d_out;
    const int nbatch = in_sizes[0] / (S * D);   // 4
    const size_t elems = (size_t)nbatch * S * D;

    // ws: kf (fp16, 2MB) | vf (bf16, 2MB) | partial[2] (fp32, 8MB) = 12MB
    const size_t need = elems * 2 * 2 + elems * 2 * 4;
    if (nbatch == 4 && ws_size >= need && d_ws != nullptr) {
        unsigned short* kf = (unsigned short*)d_ws;
        unsigned short* vf = kf + elems;
        float* partial = (float*)(vf + elems);

        prep2<<<nbatch * TILES * 2, 256, 0, stream>>>(k, v, kf, vf);
        dim3 grid(S / BQ, nbatch, 2);
        attn_main3<<<grid, 512, 0, stream>>>(q, kf, vf, partial);
        const int n4 = (int)(elems / 4);
        reduce_out<<<(n4 + 255) / 256, 256, 0, stream>>>(
            (const float4*)partial, (const float4*)(partial + elems),
            (float4*)out, n4);
    } else {
        dim3 grid(S / 64, nbatch);
        attn_fallback<<<grid, 1024, 0, stream>>>(q, k, v, out);
    }
}

// Round 6
// 91.935 us; speedup vs baseline: 4.5177x; 1.0550x over previous
//
#include <hip/hip_runtime.h>
#include <hip/hip_bf16.h>

// out = exp(Q K^T) V, unnormalized. B=4, S=4096, D=64, fp32 in/out.
// Round 6: LDS-bytes-per-MFMA targeted.
//  * BQ=128 q-rows/block: every K/V fragment read from LDS feeds 2 MFMAs
//    (2 m-tiles per wave) -> GEMM LDS reads halve vs round 5.
//  * v_permlane32_swap_b32 (gfx950) does the Sc^T C-layout -> GEMM2 A-layout
//    cross-half exchange on the VALU pipe (round 4/5's __shfl_xor put it on
//    the already-saturated LDS pipe -- why those rounds were neutral).
//  * Q pre-scaled by log2(e): exp(s) == v_exp_f32(s'), no per-score mul.
//  * Same DMA double-buffer + 1 barrier/iter + kk-split(2) + reduce kernel.

typedef short    s16x4 __attribute__((ext_vector_type(4)));
typedef short    s16x8 __attribute__((ext_vector_type(8)));
typedef _Float16 h16x8 __attribute__((ext_vector_type(8)));
typedef float    fx4   __attribute__((ext_vector_type(4)));
typedef float    fx16  __attribute__((ext_vector_type(16)));

constexpr int S = 4096, D = 64, BN = 128;
constexpr int QROWS = 128;                          // q-rows per block (main4)
constexpr int TILES = S / BN;                       // 32
constexpr int HALF_TILES = TILES / 2;               // 16 per kk-half
constexpr int TILE_SHORTS  = 16 * 512;              // 16KB per array per tile
constexpr int BATCH_SHORTS = TILES * TILE_SHORTS;   // 262144

__device__ __forceinline__ unsigned short f2bf(float x) {
    unsigned u = __float_as_uint(x);
    u = (u + 0x7FFFu + ((u >> 16) & 1u)) >> 16;   // RNE
    return (unsigned short)u;
}
__device__ __forceinline__ float bf2f(unsigned short h) {
    return __uint_as_float(((unsigned)h) << 16);
}
__device__ __forceinline__ unsigned short f2h(float x) {
    union { _Float16 h; unsigned short s; } u;
    u.h = (_Float16)x;
    return u.s;
}
__device__ __forceinline__ unsigned pack_bf16(float lo, float hi) {
    __hip_bfloat162 r = __float22bfloat162_rn(make_float2(lo, hi));
    union { __hip_bfloat162 b; unsigned u; } c;
    c.b = r;
    return c.u;
}
__device__ __forceinline__ float ex2(float x) {
#if __has_builtin(__builtin_amdgcn_exp2f)
    return __builtin_amdgcn_exp2f(x);
#else
    return exp2f(x);
#endif
}

// -------- prep: K -> fp16 A-frag order, V -> bf16 B-frag order (32x32x16) ---
// K chunk c = kkq*4+ks : [lane][j] = K[t*128 + kkq*32 + (lane&31)][ks*16 + (lane>>5)*8 + j]
// V chunk c = ss*2+dt  : [lane][j] = V[t*128 + ss*16 + (lane>>5)*8 + j][dt*32 + (lane&31)]
__global__ __launch_bounds__(256) void prep2(
    const float* __restrict__ k, const float* __restrict__ v,
    unsigned short* __restrict__ kf, unsigned short* __restrict__ vf)
{
    __shared__ unsigned short tile[128 * 72];   // row stride 72 halves (pad)
    const int tid   = threadIdx.x;
    const int which = blockIdx.x & 1;           // 0 = K, 1 = V
    const int t     = (blockIdx.x >> 1) & 31;
    const int b     = blockIdx.x >> 6;
    const float* src = (which ? v : k) + ((size_t)b * S + t * BN) * D;

    #pragma unroll
    for (int i = 0; i < 8; ++i) {               // coalesced: 2048 float4s/block
        int f   = i * 256 + tid;
        int row = f >> 4;
        int c4  = (f & 15) << 2;
        float4 x = *(const float4*)(src + row * D + c4);
        s16x4 o;
        if (which) o = (s16x4){(short)f2bf(x.x), (short)f2bf(x.y),
                               (short)f2bf(x.z), (short)f2bf(x.w)};
        else       o = (s16x4){(short)f2h(x.x), (short)f2h(x.y),
                               (short)f2h(x.z), (short)f2h(x.w)};
        *(s16x4*)&tile[row * 72 + c4] = o;
    }
    __syncthreads();

    const int lane = tid & 63;
    unsigned short* dst = (which ? vf : kf) + (size_t)b * BATCH_SHORTS + t * TILE_SHORTS;
    #pragma unroll
    for (int i = 0; i < 4; ++i) {
        int c = (tid >> 6) * 4 + i;             // chunk 0..15
        s16x8 o;
        if (which == 0) {
            int row = (c >> 2) * 32 + (lane & 31);
            int dc  = (c & 3) * 16 + (lane >> 5) * 8;
            o = *(const s16x8*)&tile[row * 72 + dc];     // b128, aligned
        } else {
            int r0 = (c >> 1) * 16 + (lane >> 5) * 8;
            int dc = (c & 1) * 32 + (lane & 31);
            #pragma unroll
            for (int j = 0; j < 8; ++j) o[j] = (short)tile[(r0 + j) * 72 + dc];
        }
        *(s16x8*)(dst + c * 512 + lane * 8) = o;         // coalesced b128
    }
}

// ---------------- main: 128 q-rows per block, one kk-half per block --------
__global__ __launch_bounds__(512, 2) void attn_main4(
    const float* __restrict__ q, const unsigned short* __restrict__ kf,
    const unsigned short* __restrict__ vf, float* __restrict__ partial)
{
    __shared__ unsigned short smem[2 * 2 * TILE_SHORTS];   // 64KB: 2 x (K 16K | V 16K)

    const int tid = threadIdx.x, lane = tid & 63, w = tid >> 6;
    const int h = lane >> 5, m5 = lane & 31;
    const int mh = w & 1, kkq = w >> 1;         // m-half (64 rows), kk-quarter
    const int b = blockIdx.y, q0 = blockIdx.x * QROWS;
    const int kh = blockIdx.z;                  // kk-half 0/1
    const int t0 = kh * HALF_TILES;

    const unsigned short* kfb = kf + (size_t)b * BATCH_SHORTS;
    const unsigned short* vfb = vf + (size_t)b * BATCH_SHORTS;

    // Q B-frags fp16, pre-scaled by log2(e) so exp(s) = exp2(s').
    // B[k=h*8+j][n=m5] = log2e * Q[q0+mh*64+mt*32+m5][ks*16+h*8+j]
    const float LOG2E = 1.4426950408889634f;
    h16x8 qf[2][4];   // [mt][ks]
    #pragma unroll
    for (int mt = 0; mt < 2; ++mt) {
        const float* qrow = q + ((size_t)b * S + q0 + mh * 64 + mt * 32 + m5) * D + h * 8;
        #pragma unroll
        for (int ks = 0; ks < 4; ++ks) {
            float4 a = *(const float4*)(qrow + ks * 16);
            float4 c = *(const float4*)(qrow + ks * 16 + 4);
            qf[mt][ks] = (h16x8){
                (_Float16)(a.x * LOG2E), (_Float16)(a.y * LOG2E),
                (_Float16)(a.z * LOG2E), (_Float16)(a.w * LOG2E),
                (_Float16)(c.x * LOG2E), (_Float16)(c.y * LOG2E),
                (_Float16)(c.z * LOG2E), (_Float16)(c.w * LOG2E)};
        }
    }

    fx16 oacc[2][2] = {};   // [mt][dt], partial over (kk-quarter, kk-half)

    auto issue = [&](int t, int bi) {
        unsigned short* base = &smem[bi * 2 * TILE_SHORTS];
        #pragma unroll
        for (int ii = 0; ii < 4; ++ii) {                 // ii<2: K, else V
            int c = (ii & 1) * 8 + w;                    // chunk 0..15
            const unsigned short* g = (ii < 2 ? kfb : vfb)
                + (size_t)t * TILE_SHORTS + c * 512 + lane * 8;
            unsigned short* l = base + (ii < 2 ? 0 : TILE_SHORTS) + c * 512 + lane * 8;
            __builtin_amdgcn_global_load_lds(
                (const __attribute__((address_space(1))) unsigned int*)g,
                (__attribute__((address_space(3))) unsigned int*)l, 16, 0, 0);
        }
    };

    issue(t0, 0);

    for (int i = 0; i < HALF_TILES; ++i) {
        const int bi = i & 1;
        // Wave's 4 DMAs of tile i (issued a full iteration ago) landed; the
        // barrier proves all waves finished reading buffer bi^1 last iter.
        __asm__ volatile("" ::: "memory");
        __builtin_amdgcn_s_waitcnt(0x0F70);   // vmcnt(0), lgkm/exp untouched
        __builtin_amdgcn_s_barrier();
        __asm__ volatile("" ::: "memory");
        if (i + 1 < HALF_TILES) issue(t0 + i + 1, bi ^ 1);

        const unsigned short* kb = &smem[bi * 2 * TILE_SHORTS];
        const unsigned short* vb = kb + TILE_SHORTS;

        // ---- GEMM1 (fp16 32x32x16): Sc^T[kk 32][m 32] x2 mt, d=64 ----
        // Each K A-frag read feeds 2 MFMAs (both m-tiles).
        fx16 sa[2] = {};
        #pragma unroll
        for (int ks = 0; ks < 4; ++ks) {
            h16x8 a = *(const h16x8*)(kb + (kkq * 4 + ks) * 512 + lane * 8);
            #pragma unroll
            for (int mt = 0; mt < 2; ++mt)
                sa[mt] = __builtin_amdgcn_mfma_f32_32x32x16_f16(a, qf[mt][ks], sa[mt], 0, 0, 0);
        }

        // ---- P = exp2(Sc^T') in regs, bf16-pair packed ----
        // C-layout: kk = (r&3) + 8*(r>>2) + 4*h, m = m5. Pair rp packs regs
        // {2rp, 2rp+1}.
        unsigned p01[2][8];
        #pragma unroll
        for (int mt = 0; mt < 2; ++mt)
            #pragma unroll
            for (int rp = 0; rp < 8; ++rp)
                p01[mt][rp] = pack_bf16(ex2(sa[mt][2 * rp]), ex2(sa[mt][2 * rp + 1]));

        // ---- C-layout -> GEMM2 A-layout: cross-half exchange ----
        // A-frag slot s (kk pair) per 16-kk step: needs own pairs + partner
        // (lane^32) pairs. v_permlane32_swap produces both halves in one op.
        union frag { unsigned u[4]; s16x8 v; };
        frag A[2][2];   // [mt][u]
        #pragma unroll
        for (int mt = 0; mt < 2; ++mt) {
#if __has_builtin(__builtin_amdgcn_permlane32_swap)
            typedef unsigned uix2 __attribute__((ext_vector_type(2)));
            uix2 r0 = __builtin_amdgcn_permlane32_swap(p01[mt][0], p01[mt][2], false, false);
            uix2 r1 = __builtin_amdgcn_permlane32_swap(p01[mt][1], p01[mt][3], false, false);
            A[mt][0].u[0] = r0.x; A[mt][0].u[1] = r1.x;
            A[mt][0].u[2] = r0.y; A[mt][0].u[3] = r1.y;
            uix2 r2 = __builtin_amdgcn_permlane32_swap(p01[mt][4], p01[mt][6], false, false);
            uix2 r3 = __builtin_amdgcn_permlane32_swap(p01[mt][5], p01[mt][7], false, false);
            A[mt][1].u[0] = r2.x; A[mt][1].u[1] = r3.x;
            A[mt][1].u[2] = r2.y; A[mt][1].u[3] = r3.y;
#else
            unsigned sw[8];
            #pragma unroll
            for (int rp = 0; rp < 8; ++rp)
                sw[rp] = (unsigned)__shfl_xor((int)p01[mt][rp], 32, 64);
            A[mt][0].u[0] = h ? sw[2]        : p01[mt][0];
            A[mt][0].u[1] = h ? sw[3]        : p01[mt][1];
            A[mt][0].u[2] = h ? p01[mt][2]   : sw[0];
            A[mt][0].u[3] = h ? p01[mt][3]   : sw[1];
            A[mt][1].u[0] = h ? sw[6]        : p01[mt][4];
            A[mt][1].u[1] = h ? sw[7]        : p01[mt][5];
            A[mt][1].u[2] = h ? p01[mt][6]   : sw[4];
            A[mt][1].u[3] = h ? p01[mt][7]   : sw[5];
#endif
        }

        // ---- GEMM2 (bf16 32x32x16): O += P*V over this wave's 32 kk ----
        // Each V B-frag read feeds 2 MFMAs (both m-tiles).
        #pragma unroll
        for (int u = 0; u < 2; ++u) {
            int ss = kkq * 2 + u;                        // 16-kk step in tile
            #pragma unroll
            for (int dt = 0; dt < 2; ++dt) {
                s16x8 vv = *(const s16x8*)(vb + (ss * 2 + dt) * 512 + lane * 8);
                #pragma unroll
                for (int mt = 0; mt < 2; ++mt)
                    oacc[mt][dt] = __builtin_amdgcn_mfma_f32_32x32x16_bf16(
                        A[mt][u].v, vv, oacc[mt][dt], 0, 0, 0);
            }
        }
    }

    // ---- epilogue: reduce 4 kk-quarters per m-half; 2 dt rounds (48KB) ----
    __syncthreads();                     // all DMA drained
    float* scratch = (float*)smem;
    float* pout = partial + ((size_t)kh * gridDim.y + b) * S * D;
    #pragma unroll
    for (int dt = 0; dt < 2; ++dt) {
        if (kkq > 0) {
            float* dst = scratch + (size_t)(mh * 3 + (kkq - 1)) * 2048;
            #pragma unroll
            for (int mt = 0; mt < 2; ++mt)
                #pragma unroll
                for (int r = 0; r < 16; ++r)
                    dst[(mt * 16 + r) * 64 + lane] = oacc[mt][dt][r];
        }
        __syncthreads();
        if (kkq == 0) {
            #pragma unroll
            for (int mt = 0; mt < 2; ++mt)
                #pragma unroll
                for (int r = 0; r < 16; ++r) {
                    float val = oacc[mt][dt][r];
                    #pragma unroll
                    for (int p = 0; p < 3; ++p)
                        val += scratch[(size_t)(mh * 3 + p) * 2048 + (mt * 16 + r) * 64 + lane];
                    int row = q0 + mh * 64 + mt * 32 + (r & 3) + 8 * (r >> 2) + 4 * h;
                    pout[(size_t)row * D + dt * 32 + m5] = val;
                }
        }
        __syncthreads();
    }
}

// ---------------- final reduce: out = partial[0] + partial[1] ----------------
__global__ __launch_bounds__(256) void reduce_out(
    const float4* __restrict__ p0, const float4* __restrict__ p1,
    float4* __restrict__ o, int n4)
{
    int i = blockIdx.x * 256 + threadIdx.x;
    if (i < n4) {
        float4 a = p0[i], b = p1[i];
        o[i] = make_float4(a.x + b.x, a.y + b.y, a.z + b.z, a.w + b.w);
    }
}

// ---------------- fallback (known-good round-2 kernel) ----------------
__global__ __launch_bounds__(1024) void attn_fallback(
    const float* __restrict__ q, const float* __restrict__ k,
    const float* __restrict__ v, float* __restrict__ out)
{
    __shared__ unsigned short Kh[64][72];
    __shared__ unsigned short Kl[64][72];
    __shared__ unsigned short Vt[64][68];
    __shared__ unsigned short Pf[64][72];

    const int tid = threadIdx.x, lane = tid & 63, wave = tid >> 6;
    const int quad = lane >> 4, tq = lane & 15;
    const int kkb = wave & 3, mba = wave >> 2;
    const int b = blockIdx.y, q0 = blockIdx.x * 64;
    const float* qb = q + (size_t)b * S * D;
    const float* kb = k + (size_t)b * S * D;
    const float* vb = v + (size_t)b * S * D;
    float* ob = out + (size_t)b * S * D;

    s16x8 qh[2], ql[2];
    {
        const float* qrow = qb + (size_t)(q0 + mba * 16 + tq) * D;
        #pragma unroll
        for (int ks = 0; ks < 2; ++ks) {
            const float* src = qrow + ks * 32 + quad * 8;
            float4 f0 = *(const float4*)src;
            float4 f1 = *(const float4*)(src + 4);
            float f[8] = {f0.x, f0.y, f0.z, f0.w, f1.x, f1.y, f1.z, f1.w};
            #pragma unroll
            for (int j = 0; j < 8; ++j) {
                unsigned short hh = f2bf(f[j]);
                qh[ks][j] = (short)hh;
                ql[ks][j] = (short)f2bf(f[j] - bf2f(hh));
            }
        }
    }
    fx4 oacc = {0.f, 0.f, 0.f, 0.f};
    const int krow = tid >> 4, kc4 = (tid & 15) << 2;
    const int vd = tid & 63, vk = (tid >> 6) << 2;

    for (int t = 0; t < S / 64; ++t) {
        __syncthreads();
        const float* kt = kb + (size_t)(t * 64 + krow) * D;
        const float* vt = vb + (size_t)(t * 64 + vk) * D;
        {
            float4 kv = *(const float4*)(kt + kc4);
            unsigned short h0 = f2bf(kv.x), h1 = f2bf(kv.y), h2 = f2bf(kv.z), h3 = f2bf(kv.w);
            s16x4 a = {(short)h0, (short)h1, (short)h2, (short)h3};
            s16x4 l4 = {(short)f2bf(kv.x - bf2f(h0)), (short)f2bf(kv.y - bf2f(h1)),
                        (short)f2bf(kv.z - bf2f(h2)), (short)f2bf(kv.w - bf2f(h3))};
            *(s16x4*)&Kh[krow][kc4] = a;
            *(s16x4*)&Kl[krow][kc4] = l4;
            const float* vs = vt + vd;
            s16x4 vv = {(short)f2bf(vs[0]), (short)f2bf(vs[D]),
                        (short)f2bf(vs[2 * D]), (short)f2bf(vs[3 * D])};
            *(s16x4*)&Vt[vd][vk] = vv;
        }
        __syncthreads();
        fx4 sacc = {0.f, 0.f, 0.f, 0.f};
        #pragma unroll
        for (int ks = 0; ks < 2; ++ks) {
            s16x8 kah = *(const s16x8*)&Kh[kkb * 16 + tq][ks * 32 + quad * 8];
            s16x8 kal = *(const s16x8*)&Kl[kkb * 16 + tq][ks * 32 + quad * 8];
            sacc = __builtin_amdgcn_mfma_f32_16x16x32_bf16(kah, qh[ks], sacc, 0, 0, 0);
            sacc = __builtin_amdgcn_mfma_f32_16x16x32_bf16(kah, ql[ks], sacc, 0, 0, 0);
            sacc = __builtin_amdgcn_mfma_f32_16x16x32_bf16(kal, qh[ks], sacc, 0, 0, 0);
        }
        s16x4 pp = {(short)f2bf(__expf(sacc[0])), (short)f2bf(__expf(sacc[1])),
                    (short)f2bf(__expf(sacc[2])), (short)f2bf(__expf(sacc[3]))};
        *(s16x4*)&Pf[mba * 16 + tq][kkb * 16 + (quad << 2)] = pp;
        __syncthreads();
        #pragma unroll
        for (int ks = 0; ks < 2; ++ks) {
            s16x8 pa = *(const s16x8*)&Pf[mba * 16 + tq][ks * 32 + quad * 8];
            const unsigned short* vr = &Vt[kkb * 16 + tq][ks * 32 + quad * 8];
            s16x4 va = *(const s16x4*)vr;
            s16x4 vb2 = *(const s16x4*)(vr + 4);
            s16x8 vfull = __builtin_shufflevector(va, vb2, 0, 1, 2, 3, 4, 5, 6, 7);
            oacc = __builtin_amdgcn_mfma_f32_16x16x32_bf16(pa, vfull, oacc, 0, 0, 0);
        }
    }
    #pragma unroll
    for (int r = 0; r < 4; ++r)
        ob[(size_t)(q0 + mba * 16 + quad * 4 + r) * D + kkb * 16 + tq] = oacc[r];
}

extern "C" void kernel_launch(void* const* d_in, const int* in_sizes, int n_in,
                              void* d_out, int out_size, void* d_ws, size_t ws_size,
                              hipStream_t stream) {
    const float* q = (const float*)d_in[0];
    const float* k = (const float*)d_in[1];
    const float* v = (const float*)d_in[2];
    float* out = (float*)d_out;
    const int nbatch = in_sizes[0] / (S * D);   // 4
    const size_t elems = (size_t)nbatch * S * D;

    // ws: kf (fp16, 2MB) | vf (bf16, 2MB) | partial[2] (fp32, 8MB) = 12MB
    const size_t need = elems * 2 * 2 + elems * 2 * 4;
    if (nbatch == 4 && ws_size >= need && d_ws != nullptr) {
        unsigned short* kf = (unsigned short*)d_ws;
        unsigned short* vf = kf + elems;
        float* partial = (float*)(vf + elems);

        prep2<<<nbatch * TILES * 2, 256, 0, stream>>>(k, v, kf, vf);
        dim3 grid(S / QROWS, nbatch, 2);
        attn_main4<<<grid, 512, 0, stream>>>(q, kf, vf, partial);
        const int n4 = (int)(elems / 4);
        reduce_out<<<(n4 + 255) / 256, 256, 0, stream>>>(
            (const float4*)partial, (const float4*)(partial + elems),
            (float4*)out, n4);
    } else {
        dim3 grid(S / 64, nbatch);
        attn_fallback<<<grid, 1024, 0, stream>>>(q, k, v, out);
    }
}